// Round 13
// baseline (241.100 us; speedup 1.0000x reference)
//
#include <hip/hip_runtime.h>
#include <cstdint>

// T=2048, D=1024, H=16, HS=64, DFF=4096. fp32 in/out, bf16 MFMA internally.

typedef __bf16 bf16;
typedef __bf16 bf16x4 __attribute__((ext_vector_type(4)));
typedef __bf16 bf16x8 __attribute__((ext_vector_type(8)));
typedef float floatx4 __attribute__((ext_vector_type(4)));

// async global->LDS 16B/lane. LDS dest is wave-uniform base + lane*16 (HW rule).
__device__ __forceinline__ void ld_g2l(const bf16* g, bf16* l) {
    __builtin_amdgcn_global_load_lds(
        (const __attribute__((address_space(1))) void*)g,
        (__attribute__((address_space(3))) void*)l, 16, 0, 0);
}

// ---------------------------------------------------------------------------
// Row LayerNorm body over D=1024: fp32 in -> bf16 out. 256 threads per row.
// ---------------------------------------------------------------------------
__device__ __forceinline__ void ln_row_body(
    const float* __restrict__ x, const float* __restrict__ sc,
    const float* __restrict__ bi, bf16* __restrict__ out,
    int row, int tid, float* wred)
{
    const float4 v = ((const float4*)(x + (size_t)row * 1024))[tid];
    float s1 = v.x + v.y + v.z + v.w;
    float s2 = v.x * v.x + v.y * v.y + v.z * v.z + v.w * v.w;
#pragma unroll
    for (int mm = 1; mm < 64; mm <<= 1) {
        s1 += __shfl_xor(s1, mm);
        s2 += __shfl_xor(s2, mm);
    }
    const int wave = tid >> 6, lane = tid & 63;
    if (lane == 0) { wred[wave] = s1; wred[4 + wave] = s2; }
    __syncthreads();
    s1 = wred[0] + wred[1] + wred[2] + wred[3];
    s2 = wred[4] + wred[5] + wred[6] + wred[7];
    const float mu = s1 * (1.f / 1024.f);
    const float var = fmaxf(s2 * (1.f / 1024.f) - mu * mu, 0.f);
    const float rr = rsqrtf(var + 1e-6f);
    const float4 scv = ((const float4*)sc)[tid];
    const float4 biv = ((const float4*)bi)[tid];
    bf16x4 ov;
    ov[0] = (bf16)((v.x - mu) * rr * scv.x + biv.x);
    ov[1] = (bf16)((v.y - mu) * rr * scv.y + biv.y);
    ov[2] = (bf16)((v.z - mu) * rr * scv.z + biv.z);
    ov[3] = (bf16)((v.w - mu) * rr * scv.w + biv.w);
    *(bf16x4*)(out + (size_t)row * 1024 + tid * 4) = ov;
}

// ---------------------------------------------------------------------------
// Prep (critical-path only): qkv weight transpose + ln1. Grid 2816 x 256:
//   [0,768)      qkv  (48 sections x 16 row-tiles, C=64)
//   [768,2816)   ln1 rows
// ---------------------------------------------------------------------------
__global__ __launch_bounds__(256) void prep_kernel(
    const float* __restrict__ Wq, const float* __restrict__ Wk,
    const float* __restrict__ Wv, bf16* __restrict__ Wqkvt,
    const float* __restrict__ x, const float* __restrict__ ln1s,
    const float* __restrict__ ln1b, bf16* __restrict__ hbuf)
{
    __shared__ float tile[64][65];
    __shared__ float wred[8];
    const int b = blockIdx.x;
    const int tid = threadIdx.x;

    if (b >= 768) {
        ln_row_body(x, ln1s, ln1b, hbuf, b - 768, tid, wred);
        return;
    }

    const int tx = tid & 63, ty = tid >> 6;
    const int sec = b >> 4, ti = b & 15;
    const int m = sec >> 4, h = sec & 15;
    const float* src = (m == 0 ? Wq : (m == 1 ? Wk : Wv)) + h * 65536;
    bf16* dst = Wqkvt + m * 1048576 + h * 65536;
    const int r0 = ti * 64;
#pragma unroll
    for (int i = ty; i < 64; i += 4)
        tile[i][tx] = src[(size_t)(r0 + i) * 64 + tx];
    __syncthreads();
#pragma unroll
    for (int i = ty; i < 64; i += 4)
        dst[(size_t)i * 1024 + r0 + tx] = (bf16)tile[tx][i];
}

// ---------------------------------------------------------------------------
// Standalone LN (ln2): LN(x1) -> h2 (bf16).
// ---------------------------------------------------------------------------
__global__ __launch_bounds__(256) void ln_kernel(
    const float* __restrict__ x, const float* __restrict__ sc,
    const float* __restrict__ bi, bf16* __restrict__ out)
{
    __shared__ float wred[8];
    ln_row_body(x, sc, bi, out, blockIdx.x, threadIdx.x, wred);
}

// ---------------------------------------------------------------------------
// Split-K reduce (4 bf16 partials):  out = p0+p1+p2+p3 + bias[col] + res
// Grid 1024 x 256, 8 elems/thread.
// ---------------------------------------------------------------------------
__global__ __launch_bounds__(256) void reduce4_kernel(
    const bf16* __restrict__ p, const float* __restrict__ bias,
    const float* __restrict__ res, float* __restrict__ out)
{
    const int idx = blockIdx.x * 256 + threadIdx.x;
    const size_t e = (size_t)idx * 8;
    const int c = (int)(e & 1023);
    const bf16x8 a0 = *(const bf16x8*)(p + e);
    const bf16x8 a1 = *(const bf16x8*)(p + 2097152 + e);
    const bf16x8 a2 = *(const bf16x8*)(p + 4194304 + e);
    const bf16x8 a3 = *(const bf16x8*)(p + 6291456 + e);
    const float4 b0 = *(const float4*)(bias + c);
    const float4 b1 = *(const float4*)(bias + c + 4);
    const float4 r0 = *(const float4*)(res + e);
    const float4 r1 = *(const float4*)(res + e + 4);
    float o[8];
#pragma unroll
    for (int i = 0; i < 8; ++i)
        o[i] = ((float)a0[i] + (float)a1[i]) + ((float)a2[i] + (float)a3[i]);
    float4 o0, o1;
    o0.x = o[0] + b0.x + r0.x; o0.y = o[1] + b0.y + r0.y;
    o0.z = o[2] + b0.z + r0.z; o0.w = o[3] + b0.w + r0.w;
    o1.x = o[4] + b1.x + r1.x; o1.y = o[5] + b1.y + r1.y;
    o1.z = o[6] + b1.z + r1.z; o1.w = o[7] + b1.w + r1.w;
    *(float4*)(out + e) = o0;
    *(float4*)(out + e + 4) = o1;
}

// ---------------------------------------------------------------------------
// 128x128 MFMA GEMM, 512 threads (8 waves): BK=64, dbuf global_load_lds, XOR
// bank swizzle, XCD swizzle <NG,MG>. Wave (w>>2, w&3) owns a 64x32 sub-tile.
// MODE 0: outB=(bf16)acc
// MODE 1: QKV+Vt fusion: bn<2048 -> outB=(bf16)acc; bn>=2048 -> Vt transposed.
// MODE 2: outB=relu(acc+bias) | MODE 3: bf16 psum outB[z*M*N+..]=(bf16)acc
// ---------------------------------------------------------------------------
template <int MODE, int NG, int MG, int SPLITK>
__global__ __launch_bounds__(512) void gemm128_kernel(
    const bf16* __restrict__ A, const bf16* __restrict__ Bt,
    int N, int K,
    float* __restrict__ outF, bf16* __restrict__ outB,
    const float* __restrict__ bias)
{
    __shared__ __align__(16) bf16 Alds[2][128][64];
    __shared__ __align__(16) bf16 Blds[2][128][64];
    const int tid  = threadIdx.x;
    const int lane = tid & 63;
    const int w    = tid >> 6;           // 0..7
    const int r15  = lane & 15;
    const int quad = lane >> 4;

    const int id    = blockIdx.x + gridDim.x * (blockIdx.y + gridDim.y * blockIdx.z);
    const int xcd   = id & 7;
    const int seq   = id >> 3;
    const int nPerX = gridDim.x / NG;
    const int mPerX = gridDim.y / MG;
    const int nm    = nPerX * mPerX;
    const int z     = seq / nm;
    const int loc   = seq - z * nm;
    const int bn    = ((xcd % NG) * nPerX + (loc % nPerX)) * 128;
    const int bm    = ((xcd / NG) * mPerX + (loc / nPerX)) * 128;

    const int wm = (w >> 2) * 64;        // 0 / 64
    const int wn = (w & 3) * 32;         // 0 / 32 / 64 / 96

    floatx4 acc[4][2];
#pragma unroll
    for (int i = 0; i < 4; ++i)
#pragma unroll
        for (int j = 0; j < 2; ++j) acc[i][j] = (floatx4)(0.f);

    const int KS    = K / SPLITK;
    const int kBase = (SPLITK > 1) ? z * KS : 0;
    const int nIter = KS / 64;

    const int lrow = lane >> 3;              // 0..7
    const int gch  = (lane & 7) ^ lrow;      // XOR-swizzled 16B chunk
    const bf16* aptr = A + (size_t)(bm + w * 16 + lrow) * K + kBase + gch * 8;
    const bf16* bptr = Bt + (size_t)(bn + w * 16 + lrow) * K + kBase + gch * 8;

#pragma unroll
    for (int t = 0; t < 2; ++t) {
        ld_g2l(aptr + (size_t)(t * 8) * K, &Alds[0][w * 16 + t * 8][0]);
        ld_g2l(bptr + (size_t)(t * 8) * K, &Blds[0][w * 16 + t * 8][0]);
    }

    for (int it = 0; it < nIter; ++it) {
        const int buf = it & 1;
        __syncthreads();
        if (it + 1 < nIter) {
            const int k2 = (it + 1) * 64;
#pragma unroll
            for (int t = 0; t < 2; ++t) {
                ld_g2l(aptr + (size_t)(t * 8) * K + k2, &Alds[buf ^ 1][w * 16 + t * 8][0]);
                ld_g2l(bptr + (size_t)(t * 8) * K + k2, &Blds[buf ^ 1][w * 16 + t * 8][0]);
            }
        }
#pragma unroll
        for (int kk = 0; kk < 2; ++kk) {
            const int pc = ((kk * 4 + quad) ^ (r15 & 7)) * 8;
            bf16x8 af[4], bfr[2];
#pragma unroll
            for (int i = 0; i < 4; ++i)
                af[i] = *(const bf16x8*)(&Alds[buf][wm + i * 16 + r15][pc]);
#pragma unroll
            for (int j = 0; j < 2; ++j)
                bfr[j] = *(const bf16x8*)(&Blds[buf][wn + j * 16 + r15][pc]);
#pragma unroll
            for (int i = 0; i < 4; ++i)
#pragma unroll
                for (int j = 0; j < 2; ++j)
                    acc[i][j] = __builtin_amdgcn_mfma_f32_16x16x32_bf16(
                        af[i], bfr[j], acc[i][j], 0, 0, 0);
        }
    }

    const int row0 = bm + wm + quad * 4;
    const int col0 = bn + wn + r15;

    if (MODE == 1 && bn >= 2048) {
        // V columns: write transposed directly to Vt[h][j][s] (s = row).
        bf16* vt = (bf16*)outF;
#pragma unroll
        for (int i = 0; i < 4; ++i) {
            const int row = row0 + i * 16;
#pragma unroll
            for (int j = 0; j < 2; ++j) {
                const int col = col0 + j * 16 - 2048;   // 0..1023
                bf16x4 pv;
#pragma unroll
                for (int reg = 0; reg < 4; ++reg) pv[reg] = (bf16)acc[i][j][reg];
                *(bf16x4*)(vt + (size_t)(col >> 6) * 131072
                              + (size_t)(col & 63) * 2048 + row) = pv;
            }
        }
        return;
    }

    bf16* po = (MODE == 3) ? outB + (size_t)z * 2097152 : outB;
#pragma unroll
    for (int i = 0; i < 4; ++i) {
#pragma unroll
        for (int reg = 0; reg < 4; ++reg) {
            const int row = row0 + i * 16 + reg;
#pragma unroll
            for (int j = 0; j < 2; ++j) {
                const int col = col0 + j * 16;
                float v = acc[i][j][reg];
                if (MODE == 0 || MODE == 1) {
                    outB[(size_t)row * N + col] = (bf16)v;
                } else if (MODE == 2) {
                    v += bias[col];
                    outB[(size_t)row * N + col] = (bf16)fmaxf(v, 0.f);
                } else {
                    po[(size_t)row * N + col] = (bf16)v;
                }
            }
        }
    }
}

// ---------------------------------------------------------------------------
// Oproj 64x64 MFMA GEMM with FUSED split-S combine on the A-operand.
// K-iter `it` == head `it`; A-tile rows bm..bm+63 == q-tile qt=bm/64, so the
// A-tile for (it,bm) is exactly Opart[0][it*32+qt] (+ Opart[1][...] if qt>0).
// outF = acc + bias[col] + res[row][col].  B staged via ld_g2l.
// ---------------------------------------------------------------------------
template <int NG, int MG>
__global__ __launch_bounds__(256) void oproj_kernel(
    const bf16* __restrict__ Opart, const float* __restrict__ Lpart,
    const bf16* __restrict__ Bt,
    float* __restrict__ outF, const float* __restrict__ bias,
    const float* __restrict__ res)
{
    const int N = 1024, K = 1024;
    __shared__ __align__(16) bf16 Alds[2][64][64];
    __shared__ __align__(16) bf16 Blds[2][64][64];
    const int tid  = threadIdx.x;
    const int lane = tid & 63;
    const int w    = tid >> 6;
    const int r15  = lane & 15;
    const int quad = lane >> 4;

    const int id    = blockIdx.x + gridDim.x * blockIdx.y;
    const int xcd   = id & 7;
    const int seq   = id >> 3;
    const int nPerX = gridDim.x / NG;
    const int mPerX = gridDim.y / MG;
    const int loc   = seq % (nPerX * mPerX);
    const int bn    = ((xcd % NG) * nPerX + (loc % nPerX)) * 64;
    const int bm    = ((xcd / NG) * mPerX + (loc / nPerX)) * 64;

    const int wm = (w >> 1) * 32;
    const int wn = (w & 1) * 32;
    const int qt = bm >> 6;                  // q-tile of this block's rows
    const bool hasB = (qt > 0);              // qt=0 has no half-1 partial

    floatx4 acc[2][2];
#pragma unroll
    for (int i = 0; i < 2; ++i)
#pragma unroll
        for (int j = 0; j < 2; ++j) acc[i][j] = (floatx4)(0.f);

    const int nIter = K / 64;                // 16 == H
    const int lrow = lane >> 3;
    const int gch  = (lane & 7) ^ lrow;
    const bf16* bptr = Bt + (size_t)(bn + w * 16 + lrow) * K + gch * 8;

    const int rit0 = w * 16 + lrow;          // t=0 row-in-tile
    const int rit1 = rit0 + 8;               // t=1 row-in-tile

    // --- prologue: stage A(it=0) + B(it=0) into buf 0 ---
#pragma unroll
    for (int t = 0; t < 2; ++t)
        ld_g2l(bptr + (size_t)(t * 8) * K, &Blds[0][w * 16 + t * 8][0]);
    {
        const size_t tb = (size_t)qt * 4096;     // head 0 tile
#pragma unroll
        for (int t = 0; t < 2; ++t) {
            const int rit = t ? rit1 : rit0;
            const size_t off = tb + (size_t)rit * 64 + gch * 8;
            const bf16x8 a = *(const bf16x8*)(Opart + off);
            float la = Lpart[qt * 64 + rit];
            bf16x8 bv; float lb = 0.f;
#pragma unroll
            for (int i = 0; i < 8; ++i) bv[i] = (bf16)0.f;
            if (hasB) {
                bv = *(const bf16x8*)(Opart + 2097152 + off);
                lb = Lpart[32768 + qt * 64 + rit];
            }
            const float inv = 1.f / (la + lb);
            bf16x8 o;
#pragma unroll
            for (int i = 0; i < 8; ++i)
                o[i] = (bf16)(((float)a[i] + (float)bv[i]) * inv);
            *(bf16x8*)(&Alds[0][w * 16 + t * 8 + lrow][(lane & 7) * 8]) = o;
        }
    }

    for (int it = 0; it < nIter; ++it) {
        const int buf = it & 1;
        __syncthreads();
        bf16x8 na[2], nb[2];
        float nla[2], nlb[2];
        const bool pf = (it + 1 < nIter);
        if (pf) {
            const int k2 = (it + 1) * 64;
#pragma unroll
            for (int t = 0; t < 2; ++t)
                ld_g2l(bptr + (size_t)(t * 8) * K + k2, &Blds[buf ^ 1][w * 16 + t * 8][0]);
            const size_t tb = (size_t)((it + 1) * 32 + qt) * 4096;
#pragma unroll
            for (int t = 0; t < 2; ++t) {
                const int rit = t ? rit1 : rit0;
                const size_t off = tb + (size_t)rit * 64 + gch * 8;
                na[t] = *(const bf16x8*)(Opart + off);
                nla[t] = Lpart[((it + 1) * 32 + qt) * 64 + rit];
#pragma unroll
                for (int i = 0; i < 8; ++i) nb[t][i] = (bf16)0.f;
                nlb[t] = 0.f;
                if (hasB) {
                    nb[t] = *(const bf16x8*)(Opart + 2097152 + off);
                    nlb[t] = Lpart[32768 + ((it + 1) * 32 + qt) * 64 + rit];
                }
            }
        }
        // MFMA phase on buf
#pragma unroll
        for (int kk = 0; kk < 2; ++kk) {
            const int pc = ((kk * 4 + quad) ^ (r15 & 7)) * 8;
            bf16x8 af[2], bfr[2];
#pragma unroll
            for (int i = 0; i < 2; ++i)
                af[i] = *(const bf16x8*)(&Alds[buf][wm + i * 16 + r15][pc]);
#pragma unroll
            for (int j = 0; j < 2; ++j)
                bfr[j] = *(const bf16x8*)(&Blds[buf][wn + j * 16 + r15][pc]);
#pragma unroll
            for (int i = 0; i < 2; ++i)
#pragma unroll
                for (int j = 0; j < 2; ++j)
                    acc[i][j] = __builtin_amdgcn_mfma_f32_16x16x32_bf16(
                        af[i], bfr[j], acc[i][j], 0, 0, 0);
        }
        // combine + ds_write A(it+1) into back buffer
        if (pf) {
#pragma unroll
            for (int t = 0; t < 2; ++t) {
                const float inv = 1.f / (nla[t] + nlb[t]);
                bf16x8 o;
#pragma unroll
                for (int i = 0; i < 8; ++i)
                    o[i] = (bf16)(((float)na[t][i] + (float)nb[t][i]) * inv);
                *(bf16x8*)(&Alds[buf ^ 1][w * 16 + t * 8 + lrow][(lane & 7) * 8]) = o;
            }
        }
    }

    const int row0 = bm + wm + quad * 4;
    const int col0 = bn + wn + r15;
#pragma unroll
    for (int i = 0; i < 2; ++i)
#pragma unroll
        for (int reg = 0; reg < 4; ++reg) {
            const int row = row0 + i * 16 + reg;
#pragma unroll
            for (int j = 0; j < 2; ++j) {
                const int col = col0 + j * 16;
                outF[(size_t)row * N + col] =
                    acc[i][j][reg] + bias[col] + res[(size_t)row * N + col];
            }
        }
}

// ---------------------------------------------------------------------------
// Split-S MFMA flash attention (causal) + CO-LAUNCHED Wo/W1/W2 transposes.
// Blocks [0,1024): attention. Blocks [1024,3328): weight transposes.
// LDS 40960 B -> 4 blocks/CU. 2-DEEP K/V pipeline: loads for step sb+2 go to
// registers at step sb start; regs for sb+1 are ds_written to buf^1 at step
// end; barrier = lgkmcnt(0) + raw s_barrier (vmcnt loads stay in flight
// across it -- no per-step vmcnt(0) drain). Reg writes LDS[r][lane&7] which
// equals the g2l XOR layout (gsw^rl = lane&7), lane-linear, conflict-free.
// ---------------------------------------------------------------------------
__global__ __launch_bounds__(256) void attn_kernel(
    const bf16* __restrict__ qkv, const bf16* __restrict__ vt,
    bf16* __restrict__ Opart, float* __restrict__ Lpart,
    const float* __restrict__ Wo, bf16* __restrict__ Wot,
    const float* __restrict__ W1, bf16* __restrict__ W1t,
    const float* __restrict__ W2, bf16* __restrict__ W2t)
{
    __shared__ __align__(16) union SM {
        struct {
            bf16 PQ[4096];          // Q staging [64][64], later P [4][16][64] swz
            bf16 Ks[2][64][64];
            bf16 Vs[2][64][64];
        } a;                        // 40960 B
        float tile[64][65];         // 16640 B (transpose role)
    } sm;

    const int tid  = threadIdx.x;
    const int b    = blockIdx.x;

    if (b >= 1024) {
        // ---- co-launched weight transpose role ----
        const int i = b - 1024;
        const float* src; bf16* dst; int R, C, c0, r0;
        if (i < 256) {
            src = Wo; dst = Wot; R = 1024; C = 1024;
            c0 = (i & 15) * 64; r0 = (i >> 4) * 64;
        } else if (i < 1280) {
            const int j = i - 256;
            src = W1; dst = W1t; R = 1024; C = 4096;
            c0 = (j & 63) * 64; r0 = (j >> 6) * 64;
        } else {
            const int j = i - 1280;
            src = W2; dst = W2t; R = 4096; C = 1024;
            c0 = (j & 15) * 64; r0 = (j >> 4) * 64;
        }
        const int tx = tid & 63, ty = tid >> 6;
#pragma unroll
        for (int k = ty; k < 64; k += 4)
            sm.tile[k][tx] = src[(size_t)(r0 + k) * C + c0 + tx];
        __syncthreads();
#pragma unroll
        for (int k = ty; k < 64; k += 4)
            dst[(size_t)(c0 + k) * R + r0 + tx] = (bf16)sm.tile[tx][k];
        return;
    }

    // ---- attention role ----
    const int w    = tid >> 6;
    const int lane = tid & 63;
    const int r15  = lane & 15;
    const int quad = lane >> 4;
    const int rl   = lane >> 3;                   // 0..7 row in 8-row group
    const int gsw  = (lane & 7) ^ (rl & 7);       // swizzled global chunk
    const int wch  = (lane & 7) * 8;              // LDS write chunk (= gsw^rl)

    const int idp  = b & 255;
    const int seq  = idp >> 3;
    const int h    = (idp & 7) * 2 + (seq & 1);   // xcd head-grouping kept
    const int qp   = seq >> 1;                    // 0..15
    const int qt   = ((b >> 8) & 1) ? 31 - qp : qp;
    const int half = b >> 9;
    const int qrow0 = qt * 64;

    // chunk bounds: [sbBeg, sbEnd) over key-steps 0..qt
    const int n0    = (qt + 2) >> 1;              // ceil((qt+1)/2)
    const int sbBeg = half ? n0 : 0;
    const int sbEnd = half ? qt + 1 : n0;

    if (sbBeg >= sbEnd) return;                   // empty chunk (qt=0, half=1)

    const int tile = half * 512 + h * 32 + qt;    // partial index
    const size_t obase = (size_t)tile * 4096;

    const bf16* qsec = qkv + h * 64;
    const bf16* ksec = qkv + 1024 + h * 64;
    const bf16* vth  = vt + (size_t)h * 64 * 2048;
    const int s0 = sbBeg * 64;
    const int wr = w * 8 + rl;                    // this lane's stage row

    // stage Q (swizzled, g2l) + K/V step sbBeg into buf 0 (g2l)
#pragma unroll
    for (int t = 0; t < 2; ++t) {
        const int r = t * 32 + w * 8 + rl;
        ld_g2l(qsec + (size_t)(qrow0 + r) * 3072 + gsw * 8, &sm.a.PQ[(t * 32 + w * 8) * 64]);
        ld_g2l(ksec + (size_t)(s0 + r) * 3072 + gsw * 8, &sm.a.Ks[0][t * 32 + w * 8][0]);
        ld_g2l(vth + (size_t)r * 2048 + s0 + gsw * 8, &sm.a.Vs[0][t * 32 + w * 8][0]);
    }
    __syncthreads();   // all g2l staging landed

    // issue reg loads for step sbBeg+1 (clamped; consumed end of first step)
    bf16x8 kA0, kA1, vA0, vA1, kB0, kB1, vB0, vB1;
    {
        const int s1 = (sbBeg + 1 < sbEnd ? sbBeg + 1 : sbEnd - 1) * 64;
        kA0 = *(const bf16x8*)(ksec + (size_t)(s1 + wr) * 3072 + gsw * 8);
        kA1 = *(const bf16x8*)(ksec + (size_t)(s1 + 32 + wr) * 3072 + gsw * 8);
        vA0 = *(const bf16x8*)(vth + (size_t)wr * 2048 + s1 + gsw * 8);
        vA1 = *(const bf16x8*)(vth + (size_t)(32 + wr) * 2048 + s1 + gsw * 8);
    }

    bf16x8 qf[2];
#pragma unroll
    for (int c = 0; c < 2; ++c) {
        const int p = ((c * 4 + quad) ^ (r15 & 7)) * 8;
        qf[c] = *(const bf16x8*)&sm.a.PQ[(w * 16 + r15) * 64 + p];
    }
    // Q region in LDS is now dead; PQ becomes the P tile from here on.

    float lacc[4] = {0.f, 0.f, 0.f, 0.f};
    floatx4 O[4];
#pragma unroll
    for (int j = 0; j < 4; ++j) O[j] = (floatx4)(0.f);

#define ATTN_STEP(CK0, CK1, CV0, CV1, NK0, NK1, NV0, NV1)                      \
    {                                                                          \
        /* issue loads for step sb+2 (clamped -> uniform vmcnt counts) */      \
        const int sld = (sb + 2 < sbEnd ? sb + 2 : sbEnd - 1) * 64;            \
        NK0 = *(const bf16x8*)(ksec + (size_t)(sld + wr) * 3072 + gsw * 8);    \
        NK1 = *(const bf16x8*)(ksec + (size_t)(sld + 32 + wr) * 3072 + gsw * 8);\
        NV0 = *(const bf16x8*)(vth + (size_t)wr * 2048 + sld + gsw * 8);       \
        NV1 = *(const bf16x8*)(vth + (size_t)(32 + wr) * 2048 + sld + gsw * 8);\
        floatx4 S[4];                                                          \
        _Pragma("unroll")                                                      \
        for (int j = 0; j < 4; ++j) S[j] = (floatx4)(0.f);                     \
        __builtin_amdgcn_s_setprio(1);                                         \
        _Pragma("unroll")                                                      \
        for (int c = 0; c < 2; ++c) {                                          \
            _Pragma("unroll")                                                  \
            for (int j = 0; j < 4; ++j) {                                      \
                const int p = ((c * 4 + quad) ^ (r15 & 7)) * 8;                \
                const bf16x8 kb = *(const bf16x8*)&sm.a.Ks[bufc][j * 16 + r15][p];\
                S[j] = __builtin_amdgcn_mfma_f32_16x16x32_bf16(qf[c], kb, S[j], 0, 0, 0);\
            }                                                                  \
        }                                                                      \
        __builtin_amdgcn_s_setprio(0);                                         \
        if (sb == qt) {                                                        \
            const int rowl = w * 16 + quad * 4;                                \
            _Pragma("unroll")                                                  \
            for (int j = 0; j < 4; ++j) {                                      \
                const int col = j * 16 + r15;                                  \
                _Pragma("unroll")                                              \
                for (int r = 0; r < 4; ++r) {                                  \
                    float pv = exp2f(fmaf(S[j][r], 0.18033688f, -28.853901f)); \
                    if (col > rowl + r) pv = 0.f;                              \
                    S[j][r] = pv;                                              \
                    lacc[r] += pv;                                             \
                }                                                              \
            }                                                                  \
        } else {                                                               \
            _Pragma("unroll")                                                  \
            for (int j = 0; j < 4; ++j)                                        \
                _Pragma("unroll")                                              \
                for (int r = 0; r < 4; ++r) {                                  \
                    const float pv = exp2f(fmaf(S[j][r], 0.18033688f, -28.853901f));\
                    S[j][r] = pv;                                              \
                    lacc[r] += pv;                                             \
                }                                                              \
        }                                                                      \
        _Pragma("unroll")                                                      \
        for (int r = 0; r < 4; ++r) {                                          \
            const int prow = quad * 4 + r;                                     \
            const int swz = (prow & 7) << 3;                                   \
            _Pragma("unroll")                                                  \
            for (int j = 0; j < 4; ++j)                                        \
                sm.a.PQ[w * 1024 + prow * 64 + ((j * 16 + r15) ^ swz)] = (bf16)S[j][r];\
        }                                                                      \
        __builtin_amdgcn_s_setprio(1);                                         \
        _Pragma("unroll")                                                      \
        for (int c = 0; c < 2; ++c) {                                          \
            const bf16x8 a = *(const bf16x8*)&sm.a.PQ[                         \
                w * 1024 + r15 * 64 + ((c * 32 + quad * 8) ^ ((r15 & 7) << 3))];\
            _Pragma("unroll")                                                  \
            for (int j = 0; j < 4; ++j) {                                      \
                const int p = ((c * 4 + quad) ^ (r15 & 7)) * 8;                \
                const bf16x8 vb = *(const bf16x8*)&sm.a.Vs[bufc][j * 16 + r15][p];\
                O[j] = __builtin_amdgcn_mfma_f32_16x16x32_bf16(a, vb, O[j], 0, 0, 0);\
            }                                                                  \
        }                                                                      \
        __builtin_amdgcn_s_setprio(0);                                         \
        /* write step sb+1's K/V (regs CUR) into back buffer */                \
        if (sb + 1 < sbEnd) {                                                  \
            const int nb_ = bufc ^ 1;                                          \
            *(bf16x8*)&sm.a.Ks[nb_][wr][wch]      = CK0;                       \
            *(bf16x8*)&sm.a.Ks[nb_][32 + wr][wch] = CK1;                       \
            *(bf16x8*)&sm.a.Vs[nb_][wr][wch]      = CV0;                       \
            *(bf16x8*)&sm.a.Vs[nb_][32 + wr][wch] = CV1;                       \
        }                                                                      \
        asm volatile("s_waitcnt lgkmcnt(0)" ::: "memory");                     \
        __builtin_amdgcn_s_barrier();                                          \
    }

    int sb = sbBeg, bufc = 0;
    while (true) {
        ATTN_STEP(kA0, kA1, vA0, vA1, kB0, kB1, vB0, vB1);
        ++sb; bufc ^= 1;
        if (sb >= sbEnd) break;
        ATTN_STEP(kB0, kB1, vB0, vB1, kA0, kA1, vA0, vA1);
        ++sb; bufc ^= 1;
        if (sb >= sbEnd) break;
    }
#undef ATTN_STEP

    // reduce l across the 16-lane row group (once per chunk)
#pragma unroll
    for (int r = 0; r < 4; ++r) {
#pragma unroll
        for (int d = 1; d < 16; d <<= 1) lacc[r] += __shfl_xor(lacc[r], d);
    }
    // epilogue: write partial O (no divide) + partial l
#pragma unroll
    for (int r = 0; r < 4; ++r) {
        const int row = w * 16 + quad * 4 + r;
#pragma unroll
        for (int j = 0; j < 4; ++j)
            Opart[obase + (size_t)row * 64 + j * 16 + r15] = (bf16)(O[j][r]);
    }
    if (r15 == 0) {
#pragma unroll
        for (int r = 0; r < 4; ++r)
            Lpart[tile * 64 + w * 16 + quad * 4 + r] = lacc[r];
    }
}

// ---------------------------------------------------------------------------
extern "C" void kernel_launch(void* const* d_in, const int* in_sizes, int n_in,
                              void* d_out, int out_size, void* d_ws, size_t ws_size,
                              hipStream_t stream)
{
    const float* x    = (const float*)d_in[0];
    const float* Wq   = (const float*)d_in[1];
    const float* Wk   = (const float*)d_in[2];
    const float* Wv   = (const float*)d_in[3];
    const float* Wo   = (const float*)d_in[4];
    const float* bo   = (const float*)d_in[5];
    const float* W1   = (const float*)d_in[6];
    const float* b1   = (const float*)d_in[7];
    const float* W2   = (const float*)d_in[8];
    const float* b2   = (const float*)d_in[9];
    const float* ln1s = (const float*)d_in[10];
    const float* ln1b = (const float*)d_in[11];
    const float* ln2s = (const float*)d_in[12];
    const float* ln2b = (const float*)d_in[13];

    char* ws = (char*)d_ws;
    bf16*  Wqkvt = (bf16*)(ws + 0);          //  6 MB [3072][1024]
    bf16*  Wot   = (bf16*)(ws + 6291456);    //  2 MB [1024][1024]
    bf16*  W1t   = (bf16*)(ws + 8388608);    //  8 MB [4096][1024]
    bf16*  W2t   = (bf16*)(ws + 16777216);   //  8 MB [1024][4096]
    bf16*  hbuf  = (bf16*)(ws + 25165824);   //  4 MB [2048][1024]
    bf16*  QKV   = (bf16*)(ws + 29360128);   // 12 MB [2048][3072] (V cols unused)
    bf16*  Vt    = (bf16*)(ws + 41943040);   //  4 MB [16][64][2048]
    float* x1    = (float*)(ws + 50331648);  //  8 MB [2048][1024]
    bf16*  h2    = (bf16*)(ws + 58720256);   //  4 MB [2048][1024]
    bf16*  ff1   = (bf16*)(ws + 62914560);   // 16 MB [2048][4096]
    bf16*  psum  = (bf16*)(ws + 79691776);   // 16 MB bf16 [4][2048][1024]
    // attn partials alias psum (attn+oproj finish before FF2 writes psum):
    bf16*  Opart = (bf16*)(ws + 79691776);   // 8.4 MB [2][512][64][64]
    float* Lpart = (float*)(ws + 96468992);  // 256 KB [2][512][64] (after psum)

    // 1. critical-path prep: qkv transpose + ln1
    prep_kernel<<<2816, 256, 0, stream>>>(Wq, Wk, Wv, Wqkvt, x, ln1s, ln1b, hbuf);
    // 2. QKV projection (BK=64, 512 threads) with fused Vt production (MODE 1)
    gemm128_kernel<1,4,2,1><<<dim3(24, 16), 512, 0, stream>>>(hbuf, Wqkvt, 3072, 1024, (float*)Vt, QKV, nullptr);
    // 3. attention (split-S, 4 blocks/CU, 2-deep pipeline) + weight transposes
    attn_kernel<<<3328, 256, 0, stream>>>(QKV, Vt, Opart, Lpart,
                                          Wo, Wot, W1, W1t, W2, W2t);
    // 4. O-projection with fused split-S combine on A (x1 = acc + bo + x)
    oproj_kernel<4,2><<<dim3(16, 32), 256, 0, stream>>>(Opart, Lpart, Wot, x1, bo, x);
    // 5. ln2
    ln_kernel<<<2048, 256, 0, stream>>>(x1, ln2s, ln2b, h2);
    // 6. FF1 with fused bias+relu (BK=64, 512 threads)
    gemm128_kernel<2,4,2,1><<<dim3(32, 16), 512, 0, stream>>>(h2, W1t, 4096, 1024, nullptr, ff1, b1);
    // 7. FF2: split-K=4, bf16 psum (BK=64, 512 threads)
    gemm128_kernel<3,2,4,4><<<dim3(8, 16, 4), 512, 0, stream>>>(ff1, W2t, 1024, 4096, nullptr, psum, nullptr);
    // 8. reduce psum + b2 + x1 -> d_out
    reduce4_kernel<<<1024, 256, 0, stream>>>(psum, b2, x1, (float*)d_out);
}

// Round 14
// 235.065 us; speedup vs baseline: 1.0257x; 1.0257x over previous
//
#include <hip/hip_runtime.h>
#include <cstdint>

// T=2048, D=1024, H=16, HS=64, DFF=4096. fp32 in/out, bf16 MFMA internally.

typedef __bf16 bf16;
typedef __bf16 bf16x4 __attribute__((ext_vector_type(4)));
typedef __bf16 bf16x8 __attribute__((ext_vector_type(8)));
typedef float floatx4 __attribute__((ext_vector_type(4)));

// async global->LDS 16B/lane. LDS dest is wave-uniform base + lane*16 (HW rule).
__device__ __forceinline__ void ld_g2l(const bf16* g, bf16* l) {
    __builtin_amdgcn_global_load_lds(
        (const __attribute__((address_space(1))) void*)g,
        (__attribute__((address_space(3))) void*)l, 16, 0, 0);
}

// ---------------------------------------------------------------------------
// Row LayerNorm body over D=1024: fp32 in -> bf16 out. 256 threads per row.
// ---------------------------------------------------------------------------
__device__ __forceinline__ void ln_row_body(
    const float* __restrict__ x, const float* __restrict__ sc,
    const float* __restrict__ bi, bf16* __restrict__ out,
    int row, int tid, float* wred)
{
    const float4 v = ((const float4*)(x + (size_t)row * 1024))[tid];
    float s1 = v.x + v.y + v.z + v.w;
    float s2 = v.x * v.x + v.y * v.y + v.z * v.z + v.w * v.w;
#pragma unroll
    for (int mm = 1; mm < 64; mm <<= 1) {
        s1 += __shfl_xor(s1, mm);
        s2 += __shfl_xor(s2, mm);
    }
    const int wave = tid >> 6, lane = tid & 63;
    if (lane == 0) { wred[wave] = s1; wred[4 + wave] = s2; }
    __syncthreads();
    s1 = wred[0] + wred[1] + wred[2] + wred[3];
    s2 = wred[4] + wred[5] + wred[6] + wred[7];
    const float mu = s1 * (1.f / 1024.f);
    const float var = fmaxf(s2 * (1.f / 1024.f) - mu * mu, 0.f);
    const float rr = rsqrtf(var + 1e-6f);
    const float4 scv = ((const float4*)sc)[tid];
    const float4 biv = ((const float4*)bi)[tid];
    bf16x4 ov;
    ov[0] = (bf16)((v.x - mu) * rr * scv.x + biv.x);
    ov[1] = (bf16)((v.y - mu) * rr * scv.y + biv.y);
    ov[2] = (bf16)((v.z - mu) * rr * scv.z + biv.z);
    ov[3] = (bf16)((v.w - mu) * rr * scv.w + biv.w);
    *(bf16x4*)(out + (size_t)row * 1024 + tid * 4) = ov;
}

// ---------------------------------------------------------------------------
// Prep (critical-path only): qkv weight transpose + ln1. Grid 2816 x 256:
//   [0,768)      qkv  (48 sections x 16 row-tiles, C=64)
//   [768,2816)   ln1 rows
// Wo/W1/W2 transposes moved into the attn launch (overlap with attention).
// ---------------------------------------------------------------------------
__global__ __launch_bounds__(256) void prep_kernel(
    const float* __restrict__ Wq, const float* __restrict__ Wk,
    const float* __restrict__ Wv, bf16* __restrict__ Wqkvt,
    const float* __restrict__ x, const float* __restrict__ ln1s,
    const float* __restrict__ ln1b, bf16* __restrict__ hbuf)
{
    __shared__ float tile[64][65];
    __shared__ float wred[8];
    const int b = blockIdx.x;
    const int tid = threadIdx.x;

    if (b >= 768) {
        ln_row_body(x, ln1s, ln1b, hbuf, b - 768, tid, wred);
        return;
    }

    const int tx = tid & 63, ty = tid >> 6;
    const int sec = b >> 4, ti = b & 15;
    const int m = sec >> 4, h = sec & 15;
    const float* src = (m == 0 ? Wq : (m == 1 ? Wk : Wv)) + h * 65536;
    bf16* dst = Wqkvt + m * 1048576 + h * 65536;
    const int r0 = ti * 64;
#pragma unroll
    for (int i = ty; i < 64; i += 4)
        tile[i][tx] = src[(size_t)(r0 + i) * 64 + tx];
    __syncthreads();
#pragma unroll
    for (int i = ty; i < 64; i += 4)
        dst[(size_t)i * 1024 + r0 + tx] = (bf16)tile[tx][i];
}

// ---------------------------------------------------------------------------
// Standalone LN (ln2): LN(x1) -> h2 (bf16).
// ---------------------------------------------------------------------------
__global__ __launch_bounds__(256) void ln_kernel(
    const float* __restrict__ x, const float* __restrict__ sc,
    const float* __restrict__ bi, bf16* __restrict__ out)
{
    __shared__ float wred[8];
    ln_row_body(x, sc, bi, out, blockIdx.x, threadIdx.x, wred);
}

// ---------------------------------------------------------------------------
// Split-K reduce (4 bf16 partials):  out = p0+p1+p2+p3 + bias[col] + res
// Grid 1024 x 256, 8 elems/thread.
// ---------------------------------------------------------------------------
__global__ __launch_bounds__(256) void reduce4_kernel(
    const bf16* __restrict__ p, const float* __restrict__ bias,
    const float* __restrict__ res, float* __restrict__ out)
{
    const int idx = blockIdx.x * 256 + threadIdx.x;
    const size_t e = (size_t)idx * 8;
    const int c = (int)(e & 1023);
    const bf16x8 a0 = *(const bf16x8*)(p + e);
    const bf16x8 a1 = *(const bf16x8*)(p + 2097152 + e);
    const bf16x8 a2 = *(const bf16x8*)(p + 4194304 + e);
    const bf16x8 a3 = *(const bf16x8*)(p + 6291456 + e);
    const float4 b0 = *(const float4*)(bias + c);
    const float4 b1 = *(const float4*)(bias + c + 4);
    const float4 r0 = *(const float4*)(res + e);
    const float4 r1 = *(const float4*)(res + e + 4);
    float o[8];
#pragma unroll
    for (int i = 0; i < 8; ++i)
        o[i] = ((float)a0[i] + (float)a1[i]) + ((float)a2[i] + (float)a3[i]);
    float4 o0, o1;
    o0.x = o[0] + b0.x + r0.x; o0.y = o[1] + b0.y + r0.y;
    o0.z = o[2] + b0.z + r0.z; o0.w = o[3] + b0.w + r0.w;
    o1.x = o[4] + b1.x + r1.x; o1.y = o[5] + b1.y + r1.y;
    o1.z = o[6] + b1.z + r1.z; o1.w = o[7] + b1.w + r1.w;
    *(float4*)(out + e) = o0;
    *(float4*)(out + e + 4) = o1;
}

// ---------------------------------------------------------------------------
// 128x128 MFMA GEMM, 512 threads (8 waves): BK=64, dbuf global_load_lds, XOR
// bank swizzle, XCD swizzle <NG,MG>. Wave (w>>2, w&3) owns a 64x32 sub-tile.
// MODE 0: outB=(bf16)acc
// MODE 1: QKV+Vt fusion: bn<2048 -> outB=(bf16)acc; bn>=2048 -> Vt transposed.
// MODE 2: outB=relu(acc+bias) | MODE 3: bf16 psum outB[z*M*N+..]=(bf16)acc
// ---------------------------------------------------------------------------
template <int MODE, int NG, int MG, int SPLITK>
__global__ __launch_bounds__(512) void gemm128_kernel(
    const bf16* __restrict__ A, const bf16* __restrict__ Bt,
    int N, int K,
    float* __restrict__ outF, bf16* __restrict__ outB,
    const float* __restrict__ bias)
{
    __shared__ __align__(16) bf16 Alds[2][128][64];
    __shared__ __align__(16) bf16 Blds[2][128][64];
    const int tid  = threadIdx.x;
    const int lane = tid & 63;
    const int w    = tid >> 6;           // 0..7
    const int r15  = lane & 15;
    const int quad = lane >> 4;

    const int id    = blockIdx.x + gridDim.x * (blockIdx.y + gridDim.y * blockIdx.z);
    const int xcd   = id & 7;
    const int seq   = id >> 3;
    const int nPerX = gridDim.x / NG;
    const int mPerX = gridDim.y / MG;
    const int nm    = nPerX * mPerX;
    const int z     = seq / nm;
    const int loc   = seq - z * nm;
    const int bn    = ((xcd % NG) * nPerX + (loc % nPerX)) * 128;
    const int bm    = ((xcd / NG) * mPerX + (loc / nPerX)) * 128;

    const int wm = (w >> 2) * 64;        // 0 / 64
    const int wn = (w & 3) * 32;         // 0 / 32 / 64 / 96

    floatx4 acc[4][2];
#pragma unroll
    for (int i = 0; i < 4; ++i)
#pragma unroll
        for (int j = 0; j < 2; ++j) acc[i][j] = (floatx4)(0.f);

    const int KS    = K / SPLITK;
    const int kBase = (SPLITK > 1) ? z * KS : 0;
    const int nIter = KS / 64;

    const int lrow = lane >> 3;              // 0..7
    const int gch  = (lane & 7) ^ lrow;      // XOR-swizzled 16B chunk
    const bf16* aptr = A + (size_t)(bm + w * 16 + lrow) * K + kBase + gch * 8;
    const bf16* bptr = Bt + (size_t)(bn + w * 16 + lrow) * K + kBase + gch * 8;

#pragma unroll
    for (int t = 0; t < 2; ++t) {
        ld_g2l(aptr + (size_t)(t * 8) * K, &Alds[0][w * 16 + t * 8][0]);
        ld_g2l(bptr + (size_t)(t * 8) * K, &Blds[0][w * 16 + t * 8][0]);
    }

    for (int it = 0; it < nIter; ++it) {
        const int buf = it & 1;
        __syncthreads();
        if (it + 1 < nIter) {
            const int k2 = (it + 1) * 64;
#pragma unroll
            for (int t = 0; t < 2; ++t) {
                ld_g2l(aptr + (size_t)(t * 8) * K + k2, &Alds[buf ^ 1][w * 16 + t * 8][0]);
                ld_g2l(bptr + (size_t)(t * 8) * K + k2, &Blds[buf ^ 1][w * 16 + t * 8][0]);
            }
        }
#pragma unroll
        for (int kk = 0; kk < 2; ++kk) {
            const int pc = ((kk * 4 + quad) ^ (r15 & 7)) * 8;
            bf16x8 af[4], bfr[2];
#pragma unroll
            for (int i = 0; i < 4; ++i)
                af[i] = *(const bf16x8*)(&Alds[buf][wm + i * 16 + r15][pc]);
#pragma unroll
            for (int j = 0; j < 2; ++j)
                bfr[j] = *(const bf16x8*)(&Blds[buf][wn + j * 16 + r15][pc]);
#pragma unroll
            for (int i = 0; i < 4; ++i)
#pragma unroll
                for (int j = 0; j < 2; ++j)
                    acc[i][j] = __builtin_amdgcn_mfma_f32_16x16x32_bf16(
                        af[i], bfr[j], acc[i][j], 0, 0, 0);
        }
    }

    const int row0 = bm + wm + quad * 4;
    const int col0 = bn + wn + r15;

    if (MODE == 1 && bn >= 2048) {
        // V columns: write transposed directly to Vt[h][j][s] (s = row).
        bf16* vt = (bf16*)outF;
#pragma unroll
        for (int i = 0; i < 4; ++i) {
            const int row = row0 + i * 16;
#pragma unroll
            for (int j = 0; j < 2; ++j) {
                const int col = col0 + j * 16 - 2048;   // 0..1023
                bf16x4 pv;
#pragma unroll
                for (int reg = 0; reg < 4; ++reg) pv[reg] = (bf16)acc[i][j][reg];
                *(bf16x4*)(vt + (size_t)(col >> 6) * 131072
                              + (size_t)(col & 63) * 2048 + row) = pv;
            }
        }
        return;
    }

    bf16* po = (MODE == 3) ? outB + (size_t)z * 2097152 : outB;
#pragma unroll
    for (int i = 0; i < 4; ++i) {
#pragma unroll
        for (int reg = 0; reg < 4; ++reg) {
            const int row = row0 + i * 16 + reg;
#pragma unroll
            for (int j = 0; j < 2; ++j) {
                const int col = col0 + j * 16;
                float v = acc[i][j][reg];
                if (MODE == 0 || MODE == 1) {
                    outB[(size_t)row * N + col] = (bf16)v;
                } else if (MODE == 2) {
                    v += bias[col];
                    outB[(size_t)row * N + col] = (bf16)fmaxf(v, 0.f);
                } else {
                    po[(size_t)row * N + col] = (bf16)v;
                }
            }
        }
    }
}

// ---------------------------------------------------------------------------
// Oproj 64x64 MFMA GEMM with FUSED split-S combine on the A-operand.
// K-iter `it` == head `it`; A-tile rows bm..bm+63 == q-tile qt=bm/64, so the
// A-tile for (it,bm) is exactly Opart[0][it*32+qt] (+ Opart[1][...] if qt>0).
// outF = acc + bias[col] + res[row][col].  B staged via ld_g2l.
// ---------------------------------------------------------------------------
template <int NG, int MG>
__global__ __launch_bounds__(256) void oproj_kernel(
    const bf16* __restrict__ Opart, const float* __restrict__ Lpart,
    const bf16* __restrict__ Bt,
    float* __restrict__ outF, const float* __restrict__ bias,
    const float* __restrict__ res)
{
    const int N = 1024, K = 1024;
    __shared__ __align__(16) bf16 Alds[2][64][64];
    __shared__ __align__(16) bf16 Blds[2][64][64];
    const int tid  = threadIdx.x;
    const int lane = tid & 63;
    const int w    = tid >> 6;
    const int r15  = lane & 15;
    const int quad = lane >> 4;

    const int id    = blockIdx.x + gridDim.x * blockIdx.y;
    const int xcd   = id & 7;
    const int seq   = id >> 3;
    const int nPerX = gridDim.x / NG;
    const int mPerX = gridDim.y / MG;
    const int loc   = seq % (nPerX * mPerX);
    const int bn    = ((xcd % NG) * nPerX + (loc % nPerX)) * 64;
    const int bm    = ((xcd / NG) * mPerX + (loc / nPerX)) * 64;

    const int wm = (w >> 1) * 32;
    const int wn = (w & 1) * 32;
    const int qt = bm >> 6;                  // q-tile of this block's rows
    const bool hasB = (qt > 0);              // qt=0 has no half-1 partial

    floatx4 acc[2][2];
#pragma unroll
    for (int i = 0; i < 2; ++i)
#pragma unroll
        for (int j = 0; j < 2; ++j) acc[i][j] = (floatx4)(0.f);

    const int nIter = K / 64;                // 16 == H
    const int lrow = lane >> 3;
    const int gch  = (lane & 7) ^ lrow;
    const bf16* bptr = Bt + (size_t)(bn + w * 16 + lrow) * K + gch * 8;

    const int rit0 = w * 16 + lrow;          // t=0 row-in-tile
    const int rit1 = rit0 + 8;               // t=1 row-in-tile

    // --- prologue: stage A(it=0) + B(it=0) into buf 0 ---
#pragma unroll
    for (int t = 0; t < 2; ++t)
        ld_g2l(bptr + (size_t)(t * 8) * K, &Blds[0][w * 16 + t * 8][0]);
    {
        const size_t tb = (size_t)qt * 4096;     // head 0 tile
#pragma unroll
        for (int t = 0; t < 2; ++t) {
            const int rit = t ? rit1 : rit0;
            const size_t off = tb + (size_t)rit * 64 + gch * 8;
            const bf16x8 a = *(const bf16x8*)(Opart + off);
            float la = Lpart[qt * 64 + rit];
            bf16x8 bv; float lb = 0.f;
#pragma unroll
            for (int i = 0; i < 8; ++i) bv[i] = (bf16)0.f;
            if (hasB) {
                bv = *(const bf16x8*)(Opart + 2097152 + off);
                lb = Lpart[32768 + qt * 64 + rit];
            }
            const float inv = 1.f / (la + lb);
            bf16x8 o;
#pragma unroll
            for (int i = 0; i < 8; ++i)
                o[i] = (bf16)(((float)a[i] + (float)bv[i]) * inv);
            *(bf16x8*)(&Alds[0][w * 16 + t * 8 + lrow][(lane & 7) * 8]) = o;
        }
    }

    for (int it = 0; it < nIter; ++it) {
        const int buf = it & 1;
        __syncthreads();
        bf16x8 na[2], nb[2];
        float nla[2], nlb[2];
        const bool pf = (it + 1 < nIter);
        if (pf) {
            const int k2 = (it + 1) * 64;
#pragma unroll
            for (int t = 0; t < 2; ++t)
                ld_g2l(bptr + (size_t)(t * 8) * K + k2, &Blds[buf ^ 1][w * 16 + t * 8][0]);
            const size_t tb = (size_t)((it + 1) * 32 + qt) * 4096;
#pragma unroll
            for (int t = 0; t < 2; ++t) {
                const int rit = t ? rit1 : rit0;
                const size_t off = tb + (size_t)rit * 64 + gch * 8;
                na[t] = *(const bf16x8*)(Opart + off);
                nla[t] = Lpart[((it + 1) * 32 + qt) * 64 + rit];
#pragma unroll
                for (int i = 0; i < 8; ++i) nb[t][i] = (bf16)0.f;
                nlb[t] = 0.f;
                if (hasB) {
                    nb[t] = *(const bf16x8*)(Opart + 2097152 + off);
                    nlb[t] = Lpart[32768 + ((it + 1) * 32 + qt) * 64 + rit];
                }
            }
        }
        // MFMA phase on buf
#pragma unroll
        for (int kk = 0; kk < 2; ++kk) {
            const int pc = ((kk * 4 + quad) ^ (r15 & 7)) * 8;
            bf16x8 af[2], bfr[2];
#pragma unroll
            for (int i = 0; i < 2; ++i)
                af[i] = *(const bf16x8*)(&Alds[buf][wm + i * 16 + r15][pc]);
#pragma unroll
            for (int j = 0; j < 2; ++j)
                bfr[j] = *(const bf16x8*)(&Blds[buf][wn + j * 16 + r15][pc]);
#pragma unroll
            for (int i = 0; i < 2; ++i)
#pragma unroll
                for (int j = 0; j < 2; ++j)
                    acc[i][j] = __builtin_amdgcn_mfma_f32_16x16x32_bf16(
                        af[i], bfr[j], acc[i][j], 0, 0, 0);
        }
        // combine + ds_write A(it+1) into back buffer
        if (pf) {
#pragma unroll
            for (int t = 0; t < 2; ++t) {
                const float inv = 1.f / (nla[t] + nlb[t]);
                bf16x8 o;
#pragma unroll
                for (int i = 0; i < 8; ++i)
                    o[i] = (bf16)(((float)na[t][i] + (float)nb[t][i]) * inv);
                *(bf16x8*)(&Alds[buf ^ 1][w * 16 + t * 8 + lrow][(lane & 7) * 8]) = o;
            }
        }
    }

    const int row0 = bm + wm + quad * 4;
    const int col0 = bn + wn + r15;
#pragma unroll
    for (int i = 0; i < 2; ++i)
#pragma unroll
        for (int reg = 0; reg < 4; ++reg) {
            const int row = row0 + i * 16 + reg;
#pragma unroll
            for (int j = 0; j < 2; ++j) {
                const int col = col0 + j * 16;
                outF[(size_t)row * N + col] =
                    acc[i][j][reg] + bias[col] + res[(size_t)row * N + col];
            }
        }
}

// ---------------------------------------------------------------------------
// Split-S MFMA flash attention (causal) + CO-LAUNCHED Wo/W1/W2 transposes.
// Blocks [0,1024): attention. Blocks [1024,3328): weight transposes.
// LDS = 40960 B exactly -> 4 blocks/CU (all 1024 attn blocks co-resident).
// Q-staging LDS is DEAD after qf register load -> unioned with the P tile
// (PQ[4096]): P stored as [4][16][64] with XOR swizzle elem ^= (row&7)<<3.
// (R13's 2-deep reg pipeline reverted: it cost VGPR 60->84, occ 34->27%,
// attn 41->48us -- TLP at 4 blocks/CU already hides the vmcnt drain.)
// ---------------------------------------------------------------------------
__global__ __launch_bounds__(256) void attn_kernel(
    const bf16* __restrict__ qkv, const bf16* __restrict__ vt,
    bf16* __restrict__ Opart, float* __restrict__ Lpart,
    const float* __restrict__ Wo, bf16* __restrict__ Wot,
    const float* __restrict__ W1, bf16* __restrict__ W1t,
    const float* __restrict__ W2, bf16* __restrict__ W2t)
{
    __shared__ __align__(16) union SM {
        struct {
            bf16 PQ[4096];          // Q staging [64][64], later P [4][16][64] swz
            bf16 Ks[2][64][64];
            bf16 Vs[2][64][64];
        } a;                        // 40960 B
        float tile[64][65];         // 16640 B (transpose role)
    } sm;

    const int tid  = threadIdx.x;
    const int b    = blockIdx.x;

    if (b >= 1024) {
        // ---- co-launched weight transpose role ----
        const int i = b - 1024;
        const float* src; bf16* dst; int R, C, c0, r0;
        if (i < 256) {
            src = Wo; dst = Wot; R = 1024; C = 1024;
            c0 = (i & 15) * 64; r0 = (i >> 4) * 64;
        } else if (i < 1280) {
            const int j = i - 256;
            src = W1; dst = W1t; R = 1024; C = 4096;
            c0 = (j & 63) * 64; r0 = (j >> 6) * 64;
        } else {
            const int j = i - 1280;
            src = W2; dst = W2t; R = 4096; C = 1024;
            c0 = (j & 15) * 64; r0 = (j >> 4) * 64;
        }
        const int tx = tid & 63, ty = tid >> 6;
#pragma unroll
        for (int k = ty; k < 64; k += 4)
            sm.tile[k][tx] = src[(size_t)(r0 + k) * C + c0 + tx];
        __syncthreads();
#pragma unroll
        for (int k = ty; k < 64; k += 4)
            dst[(size_t)(c0 + k) * R + r0 + tx] = (bf16)sm.tile[tx][k];
        return;
    }

    // ---- attention role ----
    const int w    = tid >> 6;
    const int lane = tid & 63;
    const int r15  = lane & 15;
    const int quad = lane >> 4;
    const int rl   = lane >> 3;                   // 0..7 row in 8-row group
    const int gsw  = (lane & 7) ^ (rl & 7);       // swizzled global chunk

    const int idp  = b & 255;
    const int seq  = idp >> 3;
    const int h    = (idp & 7) * 2 + (seq & 1);   // xcd head-grouping kept
    const int qp   = seq >> 1;                    // 0..15
    const int qt   = ((b >> 8) & 1) ? 31 - qp : qp;
    const int half = b >> 9;
    const int qrow0 = qt * 64;

    // chunk bounds: [sbBeg, sbEnd) over key-steps 0..qt
    const int n0    = (qt + 2) >> 1;              // ceil((qt+1)/2)
    const int sbBeg = half ? n0 : 0;
    const int sbEnd = half ? qt + 1 : n0;

    if (sbBeg >= sbEnd) return;                   // empty chunk (qt=0, half=1)

    const int tile = half * 512 + h * 32 + qt;    // partial index
    const size_t obase = (size_t)tile * 4096;

    const bf16* qsec = qkv + h * 64;
    const bf16* ksec = qkv + 1024 + h * 64;
    const bf16* vth  = vt + (size_t)h * 64 * 2048;
    const int s0 = sbBeg * 64;

    // stage Q (swizzled, g2l) + prefetch K/V step sbBeg into buf 0
#pragma unroll
    for (int t = 0; t < 2; ++t) {
        const int r = t * 32 + w * 8 + rl;
        ld_g2l(qsec + (size_t)(qrow0 + r) * 3072 + gsw * 8, &sm.a.PQ[(t * 32 + w * 8) * 64]);
        ld_g2l(ksec + (size_t)(s0 + r) * 3072 + gsw * 8, &sm.a.Ks[0][t * 32 + w * 8][0]);
        ld_g2l(vth + (size_t)r * 2048 + s0 + gsw * 8, &sm.a.Vs[0][t * 32 + w * 8][0]);
    }
    __syncthreads();   // all staging landed

    bf16x8 qf[2];
#pragma unroll
    for (int c = 0; c < 2; ++c) {
        const int p = ((c * 4 + quad) ^ (r15 & 7)) * 8;
        qf[c] = *(const bf16x8*)&sm.a.PQ[(w * 16 + r15) * 64 + p];
    }
    // Q region in LDS is now dead; PQ becomes the P tile from here on.

    float lacc[4] = {0.f, 0.f, 0.f, 0.f};
    floatx4 O[4];
#pragma unroll
    for (int j = 0; j < 4; ++j) O[j] = (floatx4)(0.f);

    int ns = 0;
#pragma unroll 1
    for (int sb = sbBeg; sb < sbEnd; ++sb, ++ns) {
        const int buf = ns & 1;
        if (sb + 1 < sbEnd) {   // prefetch next K/V into buf^1
            const int s1 = (sb + 1) * 64;
#pragma unroll
            for (int t = 0; t < 2; ++t) {
                const int r = t * 32 + w * 8 + rl;
                ld_g2l(ksec + (size_t)(s1 + r) * 3072 + gsw * 8, &sm.a.Ks[buf ^ 1][t * 32 + w * 8][0]);
                ld_g2l(vth + (size_t)r * 2048 + s1 + gsw * 8, &sm.a.Vs[buf ^ 1][t * 32 + w * 8][0]);
            }
        }

        // S = Q K^T  (wave's 16 rows x 64 keys)
        floatx4 S[4];
#pragma unroll
        for (int j = 0; j < 4; ++j) S[j] = (floatx4)(0.f);
        __builtin_amdgcn_s_setprio(1);
#pragma unroll
        for (int c = 0; c < 2; ++c) {
#pragma unroll
            for (int j = 0; j < 4; ++j) {
                const int p = ((c * 4 + quad) ^ (r15 & 7)) * 8;
                const bf16x8 kb = *(const bf16x8*)&sm.a.Ks[buf][j * 16 + r15][p];
                S[j] = __builtin_amdgcn_mfma_f32_16x16x32_bf16(qf[c], kb, S[j], 0, 0, 0);
            }
        }
        __builtin_amdgcn_s_setprio(0);
        // fixed-offset softmax: p = exp2(S*0.125*log2e - 28.854)
        if (sb == qt) {
            const int rowl = w * 16 + quad * 4;
#pragma unroll
            for (int j = 0; j < 4; ++j) {
                const int col = j * 16 + r15;
#pragma unroll
                for (int r = 0; r < 4; ++r) {
                    float p = exp2f(fmaf(S[j][r], 0.18033688f, -28.853901f));
                    if (col > rowl + r) p = 0.f;
                    S[j][r] = p;
                    lacc[r] += p;
                }
            }
        } else {
#pragma unroll
            for (int j = 0; j < 4; ++j)
#pragma unroll
                for (int r = 0; r < 4; ++r) {
                    const float p = exp2f(fmaf(S[j][r], 0.18033688f, -28.853901f));
                    S[j][r] = p;
                    lacc[r] += p;
                }
        }
        // P: C-layout -> A-layout via per-wave LDS tile in PQ (XOR-swizzled)
#pragma unroll
        for (int r = 0; r < 4; ++r) {
            const int prow = quad * 4 + r;
            const int swz = (prow & 7) << 3;
#pragma unroll
            for (int j = 0; j < 4; ++j)
                sm.a.PQ[w * 1024 + prow * 64 + ((j * 16 + r15) ^ swz)] = (bf16)S[j][r];
        }
        // O += P V
        __builtin_amdgcn_s_setprio(1);
#pragma unroll
        for (int c = 0; c < 2; ++c) {
            const bf16x8 a = *(const bf16x8*)&sm.a.PQ[
                w * 1024 + r15 * 64 + ((c * 32 + quad * 8) ^ ((r15 & 7) << 3))];
#pragma unroll
            for (int j = 0; j < 4; ++j) {
                const int p = ((c * 4 + quad) ^ (r15 & 7)) * 8;
                const bf16x8 vb = *(const bf16x8*)&sm.a.Vs[buf][j * 16 + r15][p];
                O[j] = __builtin_amdgcn_mfma_f32_16x16x32_bf16(a, vb, O[j], 0, 0, 0);
            }
        }
        __builtin_amdgcn_s_setprio(0);
        __syncthreads();  // drain prefetch (vmcnt) + protect buf reuse
    }
    // reduce l across the 16-lane row group (once per chunk)
#pragma unroll
    for (int r = 0; r < 4; ++r) {
#pragma unroll
        for (int d = 1; d < 16; d <<= 1) lacc[r] += __shfl_xor(lacc[r], d);
    }
    // epilogue: write partial O (no divide) + partial l
#pragma unroll
    for (int r = 0; r < 4; ++r) {
        const int row = w * 16 + quad * 4 + r;
#pragma unroll
        for (int j = 0; j < 4; ++j)
            Opart[obase + (size_t)row * 64 + j * 16 + r15] = (bf16)(O[j][r]);
    }
    if (r15 == 0) {
#pragma unroll
        for (int r = 0; r < 4; ++r)
            Lpart[tile * 64 + w * 16 + quad * 4 + r] = lacc[r];
    }
}

// ---------------------------------------------------------------------------
extern "C" void kernel_launch(void* const* d_in, const int* in_sizes, int n_in,
                              void* d_out, int out_size, void* d_ws, size_t ws_size,
                              hipStream_t stream)
{
    const float* x    = (const float*)d_in[0];
    const float* Wq   = (const float*)d_in[1];
    const float* Wk   = (const float*)d_in[2];
    const float* Wv   = (const float*)d_in[3];
    const float* Wo   = (const float*)d_in[4];
    const float* bo   = (const float*)d_in[5];
    const float* W1   = (const float*)d_in[6];
    const float* b1   = (const float*)d_in[7];
    const float* W2   = (const float*)d_in[8];
    const float* b2   = (const float*)d_in[9];
    const float* ln1s = (const float*)d_in[10];
    const float* ln1b = (const float*)d_in[11];
    const float* ln2s = (const float*)d_in[12];
    const float* ln2b = (const float*)d_in[13];

    char* ws = (char*)d_ws;
    bf16*  Wqkvt = (bf16*)(ws + 0);          //  6 MB [3072][1024]
    bf16*  Wot   = (bf16*)(ws + 6291456);    //  2 MB [1024][1024]
    bf16*  W1t   = (bf16*)(ws + 8388608);    //  8 MB [4096][1024]
    bf16*  W2t   = (bf16*)(ws + 16777216);   //  8 MB [1024][4096]
    bf16*  hbuf  = (bf16*)(ws + 25165824);   //  4 MB [2048][1024]
    bf16*  QKV   = (bf16*)(ws + 29360128);   // 12 MB [2048][3072] (V cols unused)
    bf16*  Vt    = (bf16*)(ws + 41943040);   //  4 MB [16][64][2048]
    float* x1    = (float*)(ws + 50331648);  //  8 MB [2048][1024]
    bf16*  h2    = (bf16*)(ws + 58720256);   //  4 MB [2048][1024]
    bf16*  ff1   = (bf16*)(ws + 62914560);   // 16 MB [2048][4096]
    bf16*  psum  = (bf16*)(ws + 79691776);   // 16 MB bf16 [4][2048][1024]
    // attn partials alias psum (attn+oproj finish before FF2 writes psum):
    bf16*  Opart = (bf16*)(ws + 79691776);   // 8.4 MB [2][512][64][64]
    float* Lpart = (float*)(ws + 96468992);  // 256 KB [2][512][64] (after psum)

    // 1. critical-path prep: qkv transpose + ln1
    prep_kernel<<<2816, 256, 0, stream>>>(Wq, Wk, Wv, Wqkvt, x, ln1s, ln1b, hbuf);
    // 2. QKV projection (BK=64, 512 threads) with fused Vt production (MODE 1)
    gemm128_kernel<1,4,2,1><<<dim3(24, 16), 512, 0, stream>>>(hbuf, Wqkvt, 3072, 1024, (float*)Vt, QKV, nullptr);
    // 3. attention (split-S, 4 blocks/CU) + co-launched Wo/W1/W2 transposes
    attn_kernel<<<3328, 256, 0, stream>>>(QKV, Vt, Opart, Lpart,
                                          Wo, Wot, W1, W1t, W2, W2t);
    // 4. O-projection with fused split-S combine on A (x1 = acc + bo + x)
    oproj_kernel<4,2><<<dim3(16, 32), 256, 0, stream>>>(Opart, Lpart, Wot, x1, bo, x);
    // 5. ln2
    ln_kernel<<<2048, 256, 0, stream>>>(x1, ln2s, ln2b, h2);
    // 6. FF1 with fused bias+relu (BK=64, 512 threads)
    gemm128_kernel<2,4,2,1><<<dim3(32, 16), 512, 0, stream>>>(h2, W1t, 4096, 1024, nullptr, ff1, b1);
    // 7. FF2: split-K=4, bf16 psum (BK=64, 512 threads)
    gemm128_kernel<3,2,4,4><<<dim3(8, 16, 4), 512, 0, stream>>>(ff1, W2t, 1024, 4096, nullptr, psum, nullptr);
    // 8. reduce psum + b2 + x1 -> d_out
    reduce4_kernel<<<1024, 256, 0, stream>>>(psum, b2, x1, (float*)d_out);
}